// Round 17
// baseline (1682.959 us; speedup 1.0000x reference)
//
#include <hip/hip_runtime.h>
#include <cstdint>
#include <cstddef>

typedef __attribute__((ext_vector_type(8))) short bf16x8;   // 8 bf16 in 4 VGPRs
typedef __attribute__((ext_vector_type(4))) float f32x4;    // MFMA accumulator

static inline int cdiv(int a, int b) { return (a + b - 1) / b; }

__device__ inline unsigned short f2bf(float f) {
    union { float f; unsigned int u; } v; v.f = f;
    unsigned int u = v.u;
    return (unsigned short)((u + 0x7FFFu + ((u >> 16) & 1u)) >> 16);  // RNE
}
__device__ inline float bf2f(unsigned short b) {
    union { unsigned int u; float f; } v; v.u = ((unsigned int)b) << 16;
    return v.f;
}

// dequant 16 biased-uint8 (excess-128) with weight*scale; caller subtracts 128*wsum.
__device__ inline void fma16u(float* a, const int4& d, float ws) {
    const unsigned int dw[4] = {(unsigned)d.x, (unsigned)d.y, (unsigned)d.z, (unsigned)d.w};
#pragma unroll
    for (int w = 0; w < 4; ++w) {
        a[w * 4 + 0] += ws * (float)(dw[w] & 0xFFu);
        a[w * 4 + 1] += ws * (float)((dw[w] >> 8) & 0xFFu);
        a[w * 4 + 2] += ws * (float)((dw[w] >> 16) & 0xFFu);
        a[w * 4 + 3] += ws * (float)(dw[w] >> 24);
    }
}

// dequant 8 biased-uint8 (int2 payload)
__device__ inline void fma8u(float* a, const int2& d, float ws) {
    const unsigned int dw[2] = {(unsigned)d.x, (unsigned)d.y};
#pragma unroll
    for (int w = 0; w < 2; ++w) {
        a[w * 4 + 0] += ws * (float)(dw[w] & 0xFFu);
        a[w * 4 + 1] += ws * (float)((dw[w] >> 8) & 0xFFu);
        a[w * 4 + 2] += ws * (float)((dw[w] >> 16) & 0xFFu);
        a[w * 4 + 3] += ws * (float)(dw[w] >> 24);
    }
}

// ---------------- prep: weight transposes (f32->bf16, [fo_pad][fi]) + zero deg/bucketCursor ----------------

struct TW {
    const float* W[9];
    int K[9];
    int N[9];
    int base[10];
    int nN;
};

__global__ __launch_bounds__(256) void prep_kernel(TW tw, unsigned short* __restrict__ Wt,
                                                   int* __restrict__ deg,
                                                   int* __restrict__ bucketCursor, int total) {
    int t = blockIdx.x * 256 + threadIdx.x;
    if (t < tw.nN) deg[t] = 0;
    if (t < 8) bucketCursor[t] = 0;
    if (t >= total) return;
    int l = 0;
#pragma unroll
    for (int i = 1; i <= 8; ++i)
        if (t >= tw.base[i]) l = i;
    int loc = t - tw.base[l];
    int K = tw.K[l], N = tw.N[l];
    int n = loc / K, k = loc - n * K;
    float v = (n < N) ? tw.W[l][(size_t)k * N + n] : 0.f;
    Wt[t] = f2bf(v);
}

// ---------------- x f32 -> bf16 (8 elems/thread, grid-stride) ----------------

__global__ __launch_bounds__(256) void cvt_x(const float* __restrict__ in,
                                             unsigned short* __restrict__ out, int n8) {
    int stride = gridDim.x * 256;
    for (int i = blockIdx.x * 256 + threadIdx.x; i < n8; i += stride) {
        const float* p = in + (size_t)i * 8;
        float4 v0 = *reinterpret_cast<const float4*>(p);
        float4 v1 = *reinterpret_cast<const float4*>(p + 4);
        bf16x8 o;
        o[0] = (short)f2bf(v0.x); o[1] = (short)f2bf(v0.y);
        o[2] = (short)f2bf(v0.z); o[3] = (short)f2bf(v0.w);
        o[4] = (short)f2bf(v1.x); o[5] = (short)f2bf(v1.y);
        o[6] = (short)f2bf(v1.z); o[7] = (short)f2bf(v1.w);
        *reinterpret_cast<bf16x8*>(out + (size_t)i * 8) = o;
    }
}

// ---------------- phase A: persistent bucket partition, wave-aggregated atomics ----------------

#define PB_BLOCKS 2048

__global__ __launch_bounds__(256) void partition_v2(
        const int* __restrict__ src, const int* __restrict__ dst,
        const float* __restrict__ w,
        int* __restrict__ bucketCursor, int4* __restrict__ staging,
        int bucketCap, int nE, int nN) {
    __shared__ int cnt[8];
    __shared__ int cur[8];
    const int tid = threadIdx.x;
    const int lane = tid & 63;
    const int perBlock = (nE + (int)gridDim.x - 1) / (int)gridDim.x;
    const int begE = blockIdx.x * perBlock;
    const int endE = (begE + perBlock < nE) ? begE + perBlock : nE;
    if (begE >= endE) return;
    if (tid < 8) cnt[tid] = 0;
    __syncthreads();
    for (int i = begE + tid; i < endE; i += 256) {
        int d = dst[i];
        int b = (int)(((long long)d * 8) / nN);
#pragma unroll
        for (int bb = 0; bb < 8; ++bb) {
            unsigned long long mask = __ballot(b == bb);
            if (mask && lane == (__ffsll(mask) - 1))
                atomicAdd(&cnt[bb], (int)__popcll(mask));
        }
    }
    __syncthreads();
    if (tid < 8) cur[tid] = atomicAdd(&bucketCursor[tid], cnt[tid]);
    __syncthreads();
    for (int i = begE + tid; i < endE; i += 256) {
        int d = dst[i], s = src[i];
        float wv = w[i];
        int b = (int)(((long long)d * 8) / nN);
        int pos = 0;
#pragma unroll
        for (int bb = 0; bb < 8; ++bb) {
            unsigned long long mask = __ballot(b == bb);
            int leader = mask ? (__ffsll(mask) - 1) : 0;
            int base_bb = 0;
            if (mask && lane == leader) base_bb = atomicAdd(&cur[bb], (int)__popcll(mask));
            base_bb = __shfl(base_bb, leader);
            if (b == bb) pos = base_bb + (int)__popcll(mask & ((1ull << lane) - 1ull));
        }
        staging[(size_t)b * bucketCap + pos] = make_int4(d, s, __float_as_int(wv), 0);
    }
}

// ---------------- bucketed deg count: LDS histogram per block, coalesced flush ----------------

#define DC_BPB 32

__global__ __launch_bounds__(256) void deg_count(const int4* __restrict__ staging,
                                                 const int* __restrict__ bucketCnt,
                                                 int bucketCap, int* __restrict__ deg, int nN) {
    __shared__ int hist[12512];
    int bucket = blockIdx.x & 7;
    int chunk = blockIdx.x >> 3;
    int cnt = bucketCnt[bucket];
    int lo = (int)(((long long)bucket * nN + 7) / 8);
    int hi = (int)(((long long)(bucket + 1) * nN + 7) / 8);
    if (hi > nN) hi = nN;
    int span = hi - lo;
    for (int i = threadIdx.x; i < span; i += 256) hist[i] = 0;
    __syncthreads();
    const int4* st = staging + (size_t)bucket * bucketCap;
    for (int i = chunk * 256 + threadIdx.x; i < cnt; i += DC_BPB * 256)
        atomicAdd(&hist[st[i].x - lo], 1);
    __syncthreads();
    for (int i = threadIdx.x; i < span; i += 256) {
        int v = hist[i];
        if (v) atomicAdd(&deg[lo + i], v);
    }
}

// ---------------- scan: per-block sums, then fused (partial-scan + final) ----------------

__global__ __launch_bounds__(256) void scan_part(const int* __restrict__ deg,
                                                 int* __restrict__ partials, int n) {
    __shared__ int sdata[256];
    int tid = threadIdx.x;
    int base = blockIdx.x * 1024;
    int local = 0;
#pragma unroll
    for (int i = 0; i < 4; ++i) {
        int idx = base + tid * 4 + i;
        local += (idx < n) ? deg[idx] : 0;
    }
    sdata[tid] = local;
    __syncthreads();
    for (int off = 128; off; off >>= 1) {
        if (tid < off) sdata[tid] += sdata[tid + off];
        __syncthreads();
    }
    if (tid == 0) partials[blockIdx.x] = sdata[0];
}

__global__ __launch_bounds__(256) void scan_final2(const int* __restrict__ deg,
                                                   const int* __restrict__ partials,
                                                   int* __restrict__ rowptr,
                                                   int* __restrict__ cursor, int n, int nb) {
    __shared__ int ps[128];
    __shared__ int sdata[256];
    int tid = threadIdx.x;
    if (tid < 128) ps[tid] = (tid < nb) ? partials[tid] : 0;
    __syncthreads();
    for (int off = 1; off < 128; off <<= 1) {
        int t = (tid < 128 && tid >= off) ? ps[tid - off] : 0;
        __syncthreads();
        if (tid < 128) ps[tid] += t;
        __syncthreads();
    }
    int base = (blockIdx.x == 0) ? 0 : ps[blockIdx.x - 1];
    if (blockIdx.x == 0 && tid == 0) rowptr[n] = ps[nb - 1];
    int bb = blockIdx.x * 1024;
    int vals[4];
    int local = 0;
#pragma unroll
    for (int i = 0; i < 4; ++i) {
        int idx = bb + tid * 4 + i;
        vals[i] = (idx < n) ? deg[idx] : 0;
        local += vals[i];
    }
    sdata[tid] = local;
    __syncthreads();
    for (int off = 1; off < 256; off <<= 1) {
        int t = (tid >= off) ? sdata[tid - off] : 0;
        __syncthreads();
        sdata[tid] += t;
        __syncthreads();
    }
    int run = sdata[tid] - local + base;
#pragma unroll
    for (int i = 0; i < 4; ++i) {
        int idx = bb + tid * 4 + i;
        if (idx < n) { rowptr[idx] = run; cursor[idx] = run; }
        run += vals[i];
    }
}

// ---------------- phase B: per-bucket scatter (bucket b on blocks bid%8==b) ----------------

__global__ __launch_bounds__(256) void scatter_b(const int4* __restrict__ staging,
                                                 const int* __restrict__ bucketCnt,
                                                 int bucketCap, int* __restrict__ cursor,
                                                 int2* __restrict__ ep, int blocksPerBucket) {
    int bucket = blockIdx.x & 7;
    int chunk = blockIdx.x >> 3;
    int cnt = bucketCnt[bucket];
    const int4* st = staging + (size_t)bucket * bucketCap;
    for (int i = chunk * 256 + threadIdx.x; i < cnt; i += blocksPerBucket * 256) {
        int4 r = st[i];
        int pos = atomicAdd(&cursor[r.x], 1);
        ep[pos] = make_int2(r.y, r.z);
    }
}

// ---------------- bf16 MFMA GEMM (m97 structure): C[M,N] = A[M,K] @ Bt[N,K]^T ----------------
// OUTQ: 0 = bf16 out; 1 = biased-uint8 out, per-(row,128-col-block) scale (BN=128);
//       2 = biased-uint8 out, per-row scale (BN=64, single column block).

template <int BN, bool AF32, int OUTQ>
__global__ __launch_bounds__(256) void gemm_mfma(const void* __restrict__ Av,
                                                 const unsigned short* __restrict__ Bt,
                                                 void* __restrict__ Cv,
                                                 float* __restrict__ scArr,
                                                 int M, int K, int N) {
    constexpr int BM = 128, BK = 64;
    __shared__ unsigned short As[BM * BK];
    __shared__ unsigned short Bs[BN * BK];
    const int tid = threadIdx.x;
    const int lane = tid & 63, wid = tid >> 6;
    const int m0 = blockIdx.x * BM, n0 = blockIdx.y * BN;

    constexpr int WN = (BN == 128) ? 2 : 1;
    constexpr int WTM = (BN == 128) ? 64 : 32;
    constexpr int FM = WTM / 16, FN = 4;
    const int wm = (wid / WN) * WTM;
    const int wn = (wid % WN) * 64;
    const int g = lane >> 4, r16 = lane & 15;

    const unsigned short* A16 = (const unsigned short*)Av;
    const float* A32 = (const float*)Av;

    f32x4 acc[FM][FN] = {};

    for (int k0 = 0; k0 < K; k0 += BK) {
        if constexpr (AF32) {
#pragma unroll
            for (int it = 0; it < 4; ++it) {
                int c = it * 256 + tid;
                int r = c >> 3, kc = c & 7;
                int gm = m0 + r;
                bf16x8 val;
                if (gm < M) {
                    const float* p = A32 + (size_t)gm * K + k0 + kc * 8;
                    float4 v0 = *reinterpret_cast<const float4*>(p);
                    float4 v1 = *reinterpret_cast<const float4*>(p + 4);
                    val[0] = (short)f2bf(v0.x); val[1] = (short)f2bf(v0.y);
                    val[2] = (short)f2bf(v0.z); val[3] = (short)f2bf(v0.w);
                    val[4] = (short)f2bf(v1.x); val[5] = (short)f2bf(v1.y);
                    val[6] = (short)f2bf(v1.z); val[7] = (short)f2bf(v1.w);
                } else {
#pragma unroll
                    for (int j = 0; j < 8; ++j) val[j] = 0;
                }
                *reinterpret_cast<bf16x8*>(&As[r * BK + kc * 8]) = val;
            }
        } else {
#pragma unroll
            for (int c = 0; c < 4; ++c) {
                int base = wid * 32 + c * 8;
                int row = base + (lane >> 3), kc = lane & 7;
                const unsigned short* gp = A16 + (size_t)(m0 + row) * K + k0 + kc * 8;
                __builtin_amdgcn_global_load_lds(
                    (const __attribute__((address_space(1))) void*)gp,
                    (__attribute__((address_space(3))) void*)&As[base * BK], 16, 0, 0);
            }
        }
        {
            constexpr int BCALLS = (BN * BK) / (512 * 4);
#pragma unroll
            for (int c = 0; c < BCALLS; ++c) {
                int base = wid * (BN / 4) + c * 8;
                int row = base + (lane >> 3), kc = lane & 7;
                const unsigned short* gp = Bt + (size_t)(n0 + row) * K + k0 + kc * 8;
                __builtin_amdgcn_global_load_lds(
                    (const __attribute__((address_space(1))) void*)gp,
                    (__attribute__((address_space(3))) void*)&Bs[base * BK], 16, 0, 0);
            }
        }
        __syncthreads();
#pragma unroll
        for (int ks = 0; ks < 2; ++ks) {
            bf16x8 af[FM], bfr[FN];
#pragma unroll
            for (int i = 0; i < FM; ++i)
                af[i] = *reinterpret_cast<const bf16x8*>(&As[(wm + i * 16 + r16) * BK + ks * 32 + g * 8]);
#pragma unroll
            for (int j = 0; j < FN; ++j)
                bfr[j] = *reinterpret_cast<const bf16x8*>(&Bs[(wn + j * 16 + r16) * BK + ks * 32 + g * 8]);
#pragma unroll
            for (int i = 0; i < FM; ++i)
#pragma unroll
                for (int j = 0; j < FN; ++j)
                    acc[i][j] = __builtin_amdgcn_mfma_f32_16x16x32_bf16(af[i], bfr[j], acc[i][j], 0, 0, 0);
        }
        __syncthreads();
    }

    if constexpr (OUTQ == 1) {
        __shared__ float rmax2[2][BM];
        const int wc = wid % WN;
        unsigned char* C8 = (unsigned char*)Cv;
#pragma unroll
        for (int i = 0; i < FM; ++i) {
#pragma unroll
            for (int r = 0; r < 4; ++r) {
                float m = 0.f;
#pragma unroll
                for (int j = 0; j < FN; ++j) m = fmaxf(m, fabsf(acc[i][j][r]));
                m = fmaxf(m, __shfl_xor(m, 1));
                m = fmaxf(m, __shfl_xor(m, 2));
                m = fmaxf(m, __shfl_xor(m, 4));
                m = fmaxf(m, __shfl_xor(m, 8));
                if (r16 == 0) rmax2[wc][wm + i * 16 + g * 4 + r] = m;
            }
        }
        __syncthreads();
#pragma unroll
        for (int i = 0; i < FM; ++i) {
#pragma unroll
            for (int r = 0; r < 4; ++r) {
                int rl = wm + i * 16 + g * 4 + r;
                float rm = fmaxf(rmax2[0][rl], rmax2[1][rl]);
                float inv = (rm > 0.f) ? 127.f / rm : 0.f;
                int gm = m0 + rl;
                if (gm < M) {
                    if (wc == 0 && r16 == 0)
                        scArr[(size_t)gm * 2 + blockIdx.y] = rm * (1.f / 127.f);
#pragma unroll
                    for (int j = 0; j < FN; ++j) {
                        int gn = n0 + wn + j * 16 + r16;
                        float q = fminf(fmaxf(rintf(acc[i][j][r] * inv), -127.f), 127.f);
                        C8[(size_t)gm * N + gn] = (unsigned char)((int)q + 128);
                    }
                }
            }
        }
    } else if constexpr (OUTQ == 2) {
        unsigned char* C8 = (unsigned char*)Cv;
#pragma unroll
        for (int i = 0; i < FM; ++i) {
#pragma unroll
            for (int r = 0; r < 4; ++r) {
                float m = 0.f;
#pragma unroll
                for (int j = 0; j < FN; ++j) m = fmaxf(m, fabsf(acc[i][j][r]));
                m = fmaxf(m, __shfl_xor(m, 1));
                m = fmaxf(m, __shfl_xor(m, 2));
                m = fmaxf(m, __shfl_xor(m, 4));
                m = fmaxf(m, __shfl_xor(m, 8));
                float inv = (m > 0.f) ? 127.f / m : 0.f;
                int gm = m0 + wm + i * 16 + g * 4 + r;
                if (gm < M) {
                    if (r16 == 0) scArr[(size_t)gm * 2] = m * (1.f / 127.f);
#pragma unroll
                    for (int j = 0; j < FN; ++j) {
                        int gn = wn + j * 16 + r16;
                        float q = fminf(fmaxf(rintf(acc[i][j][r] * inv), -127.f), 127.f);
                        C8[(size_t)gm * 64 + gn] = (unsigned char)((int)q + 128);
                    }
                }
            }
        }
    } else {
        unsigned short* C = (unsigned short*)Cv;
#pragma unroll
        for (int i = 0; i < FM; ++i) {
            int gmBase = m0 + wm + i * 16 + g * 4;
#pragma unroll
            for (int j = 0; j < FN; ++j) {
                int gn = n0 + wn + j * 16 + r16;
                if (gn < N) {
#pragma unroll
                    for (int r = 0; r < 4; ++r) {
                        int gm = gmBase + r;
                        if (gm < M) C[(size_t)gm * N + gn] = f2bf(acc[i][j][r]);
                    }
                }
            }
        }
    }
}

// ---------------- biased-uint8 CSR aggregation, persistent grid-stride waves ----------------

template <int FO>
__global__ __launch_bounds__(256) void agg_q8(const char* __restrict__ supp8,
                                              const float* __restrict__ sc,
                                              const int2* __restrict__ ep,
                                              const int* __restrict__ rowptr,
                                              const float* __restrict__ bias,
                                              unsigned short* __restrict__ out, int n_nodes) {
    constexpr int LPR = FO / 16;
    constexpr int EPS = 64 / LPR;
    constexpr int G16 = 16 / EPS;
    constexpr int G8 = 8 / EPS;
    constexpr int TG = (FO == 256) ? 2 : 1;
    const int wave0 = (int)((blockIdx.x * blockDim.x + threadIdx.x) >> 6);
    const int nWaves = (int)((gridDim.x * blockDim.x) >> 6);
    const int lane = threadIdx.x & 63;
    const int lr = lane & (LPR - 1);
    const int half = lane / LPR;
    const int hi = (FO == 256) ? (lr >> 3) : 0;

    for (int node = wave0; node < n_nodes; node += nWaves) {
        int beg = __builtin_amdgcn_readfirstlane(rowptr[node]);
        int end = __builtin_amdgcn_readfirstlane(rowptr[node + 1]);
        float a[16] = {};
        float wsum = 0.f;
        int e = beg;
        for (; e + 16 <= end; e += 16) {
            int2 me[G16];
#pragma unroll
            for (int u = 0; u < G16; ++u) me[u] = ep[e + u * EPS + half];
            float ss[G16];
            int4 q[G16];
#pragma unroll
            for (int u = 0; u < G16; ++u) ss[u] = sc[(size_t)me[u].x * 2 + hi];
#pragma unroll
            for (int u = 0; u < G16; ++u)
                q[u] = *reinterpret_cast<const int4*>(supp8 + (size_t)me[u].x * FO + lr * 16);
#pragma unroll
            for (int u = 0; u < G16; ++u) {
                float ws = __int_as_float(me[u].y) * ss[u];
                fma16u(a, q[u], ws);
                wsum += ws;
            }
        }
        if constexpr (G8 >= 1) {
            for (; e + 8 <= end; e += 8) {
                int2 me[G8];
#pragma unroll
                for (int u = 0; u < G8; ++u) me[u] = ep[e + u * EPS + half];
                float ss[G8];
                int4 q[G8];
#pragma unroll
                for (int u = 0; u < G8; ++u) ss[u] = sc[(size_t)me[u].x * 2 + hi];
#pragma unroll
                for (int u = 0; u < G8; ++u)
                    q[u] = *reinterpret_cast<const int4*>(supp8 + (size_t)me[u].x * FO + lr * 16);
#pragma unroll
                for (int u = 0; u < G8; ++u) {
                    float ws = __int_as_float(me[u].y) * ss[u];
                    fma16u(a, q[u], ws);
                    wsum += ws;
                }
            }
        }
        {
            int rem = end - e;
            if (rem > 0) {
#pragma unroll
                for (int u = 0; u < TG; ++u) {
                    int idx = u * EPS + half;
                    bool ok = idx < rem;
                    int2 me = ep[e + (ok ? idx : 0)];
                    float ws = ok ? __int_as_float(me.y) * sc[(size_t)me.x * 2 + hi] : 0.f;
                    int4 q = *reinterpret_cast<const int4*>(supp8 + (size_t)me.x * FO + lr * 16);
                    fma16u(a, q, ws);
                    wsum += ws;
                }
            }
        }
#pragma unroll
        for (int j = 0; j < 16; ++j) a[j] -= 128.f * wsum;
#pragma unroll
        for (int off = LPR; off < 64; off <<= 1)
#pragma unroll
            for (int j = 0; j < 16; ++j) a[j] += __shfl_xor(a[j], off);
        if (lane < LPR) {
            float bb[16];
#pragma unroll
            for (int c = 0; c < 4; ++c) {
                float4 bv = *reinterpret_cast<const float4*>(bias + lr * 16 + c * 4);
                bb[c * 4 + 0] = bv.x; bb[c * 4 + 1] = bv.y;
                bb[c * 4 + 2] = bv.z; bb[c * 4 + 3] = bv.w;
            }
            bf16x8 o0, o1;
#pragma unroll
            for (int j = 0; j < 8; ++j) {
                o0[j] = (short)f2bf(fmaxf(a[j] + bb[j], 0.f));
                o1[j] = (short)f2bf(fmaxf(a[j + 8] + bb[j + 8], 0.f));
            }
            unsigned short* op = out + (size_t)node * FO + lr * 16;
            *reinterpret_cast<bf16x8*>(op) = o0;
            *reinterpret_cast<bf16x8*>(op + 8) = o1;
        }
    }
}

// ---------------- final layer: uint8 supp (64 B rows, per-row scale), agg + log_softmax ----------------
// 8 lanes/row (8B int2 loads), 8 edges parallel, grid-stride waves.

__global__ __launch_bounds__(256) void agg_lsm_q8(const char* __restrict__ supp8,
                                                  const float* __restrict__ sc,
                                                  const int2* __restrict__ ep,
                                                  const int* __restrict__ rowptr,
                                                  const float* __restrict__ bias,
                                                  float* __restrict__ out, int n_nodes) {
    const int wave0 = (int)((blockIdx.x * blockDim.x + threadIdx.x) >> 6);
    const int nWaves = (int)((gridDim.x * blockDim.x) >> 6);
    const int lane = threadIdx.x & 63;
    const int lr = lane & 7;
    const int half = lane >> 3;

    for (int node = wave0; node < n_nodes; node += nWaves) {
        int beg = __builtin_amdgcn_readfirstlane(rowptr[node]);
        int end = __builtin_amdgcn_readfirstlane(rowptr[node + 1]);
        float a[8] = {};
        float wsum = 0.f;
        int e = beg;
        for (; e + 16 <= end; e += 16) {
            int2 me0 = ep[e + half];
            int2 me1 = ep[e + 8 + half];
            float s0 = sc[(size_t)me0.x * 2];
            float s1 = sc[(size_t)me1.x * 2];
            int2 q0 = *reinterpret_cast<const int2*>(supp8 + (size_t)me0.x * 64 + lr * 8);
            int2 q1 = *reinterpret_cast<const int2*>(supp8 + (size_t)me1.x * 64 + lr * 8);
            float w0 = __int_as_float(me0.y) * s0;
            float w1 = __int_as_float(me1.y) * s1;
            fma8u(a, q0, w0);
            fma8u(a, q1, w1);
            wsum += w0 + w1;
        }
        {   // guarded vector tail (rem < 16)
            int rem = end - e;
            if (rem > 0) {
#pragma unroll
                for (int u = 0; u < 2; ++u) {
                    int idx = u * 8 + half;
                    bool ok = idx < rem;
                    int2 me = ep[e + (ok ? idx : 0)];
                    float ws = ok ? __int_as_float(me.y) * sc[(size_t)me.x * 2] : 0.f;
                    int2 q = *reinterpret_cast<const int2*>(supp8 + (size_t)me.x * 64 + lr * 8);
                    fma8u(a, q, ws);
                    wsum += ws;
                }
            }
        }
#pragma unroll
        for (int off = 8; off < 64; off <<= 1) {
#pragma unroll
            for (int j = 0; j < 8; ++j) a[j] += __shfl_xor(a[j], off);
            wsum += __shfl_xor(wsum, off);
        }
#pragma unroll
        for (int j = 0; j < 8; ++j) a[j] -= 128.f * wsum;
        float vj[8];
#pragma unroll
        for (int j = 0; j < 8; ++j) {
            int col = lane * 8 + j;
            float bv = (lane < 8 && col < 40) ? bias[col] : 0.f;
            vj[j] = (col < 40) ? (a[j] + bv) : -1e30f;
        }
        float m = vj[0];
#pragma unroll
        for (int j = 1; j < 8; ++j) m = fmaxf(m, vj[j]);
#pragma unroll
        for (int off = 1; off < 8; off <<= 1) m = fmaxf(m, __shfl_xor(m, off));
        float s = 0.f;
#pragma unroll
        for (int j = 0; j < 8; ++j) s += expf(vj[j] - m);
#pragma unroll
        for (int off = 1; off < 8; off <<= 1) s += __shfl_xor(s, off);
        float ls = m + logf(s);
        if (lane < 5) {
            float4 o0, o1;
            o0.x = vj[0] - ls; o0.y = vj[1] - ls; o0.z = vj[2] - ls; o0.w = vj[3] - ls;
            o1.x = vj[4] - ls; o1.y = vj[5] - ls; o1.z = vj[6] - ls; o1.w = vj[7] - ls;
            float* op = out + (size_t)node * 40 + lane * 8;
            *reinterpret_cast<float4*>(op) = o0;
            *reinterpret_cast<float4*>(op + 4) = o1;
        }
    }
}

// ---------------- launch ----------------

extern "C" void kernel_launch(void* const* d_in, const int* in_sizes, int n_in,
                              void* d_out, int out_size, void* d_ws, size_t ws_size,
                              hipStream_t stream) {
    const float* x    = (const float*)d_in[0];
    const int*   esrc = (const int*)d_in[1];
    const int*   edst = (const int*)d_in[2];
    const float* ew   = (const float*)d_in[3];

    const int nN = in_sizes[0] / 512;  // 100000
    const int nE = in_sizes[1];        // 3200000

    const int dims[10] = {512, 256, 256, 256, 256, 256, 128, 128, 64, 40};
    const int BUCKET_CAP = ((nE / 8) + (nE / 64) + 4095) & ~4095;

    // ---- workspace layout (gload_lds A-tile tail reads overrun ~100 KB past h/xbf;
    // live regions follow both) ----
    const size_t Sh    = (size_t)nN * 512;        // h (bf16)
    const size_t Ssupp = (size_t)nN * 512;        // supp region
    const size_t Sxbf  = (size_t)nN * 1024;       // optional x as bf16
    const size_t Srest = (size_t)(1 << 21)                      // Wt
                       + (size_t)nN * 8 + 256                   // scArr
                       + (size_t)8 * BUCKET_CAP * 16            // staging
                       + 3 * ((size_t)nN + 64) * 4              // deg/rowptr/cursor
                       + 128 * 4 + 64 * 4                       // partials/bucketCursor
                       + (size_t)nE * 8;                        // ep
    const bool useXbf = ws_size >= Sh + Ssupp + Sxbf + Srest;

    char* ws = (char*)d_ws;
    unsigned short* h    = (unsigned short*)ws;
    unsigned short* supp = (unsigned short*)(ws + Sh);
    char* supp8 = (char*)supp;
    char* p = ws + Sh + Ssupp;
    unsigned short* xbf = (unsigned short*)p; if (useXbf) p += Sxbf;
    unsigned short* Wt = (unsigned short*)p; p += (1 << 21);
    float* scArr  = (float*)p; p += (size_t)nN * 8 + 256;
    int4* staging = (int4*)p; p += (size_t)8 * BUCKET_CAP * 16;
    int* deg      = (int*)p; p += ((size_t)nN + 64) * 4;
    int* rowptr   = (int*)p; p += ((size_t)nN + 64) * 4;
    int* cursor   = (int*)p; p += ((size_t)nN + 64) * 4;
    int* partials = (int*)p; p += 128 * 4;
    int* bucketCursor = (int*)p; p += 64 * 4;
    int2* ep      = (int2*)p; p += (size_t)nE * 8;

    // ---- prep: transpose+convert weights, zero deg/bucketCursor ----
    TW tw;
    size_t woff[9];
    {
        int off = 0;
        for (int i = 0; i < 9; ++i) {
            tw.W[i] = (const float*)d_in[4 + 2 * i];
            tw.K[i] = dims[i];
            tw.N[i] = dims[i + 1];
            tw.base[i] = off;
            woff[i] = (size_t)off;
            int fop = cdiv(dims[i + 1], 64) * 64;
            off += fop * dims[i];
        }
        tw.base[9] = off;
        tw.nN = nN;
        int total = off;
        int nPrep = cdiv((total > nN + 8) ? total : nN + 8, 256);
        prep_kernel<<<nPrep, 256, 0, stream>>>(tw, Wt, deg, bucketCursor, total);
    }
    const float* b[9];
    for (int i = 0; i < 9; ++i) b[i] = (const float*)d_in[5 + 2 * i];

    // ---- optional x -> bf16 conversion (for fast L0 gload_lds path) ----
    if (useXbf)
        cvt_x<<<2048, 256, 0, stream>>>(x, xbf, nN * 64);  // nN*512/8 chunks

    // ---- CSR build: partition_v2 -> bucketed deg count -> scan -> per-bucket scatter ----
    partition_v2<<<PB_BLOCKS, 256, 0, stream>>>(esrc, edst, ew, bucketCursor,
                                                staging, BUCKET_CAP, nE, nN);
    deg_count<<<8 * DC_BPB, 256, 0, stream>>>(staging, bucketCursor, BUCKET_CAP, deg, nN);
    {
        int nb = cdiv(nN, 1024);
        scan_part<<<nb, 256, 0, stream>>>(deg, partials, nN);
        scan_final2<<<nb, 256, 0, stream>>>(deg, partials, rowptr, cursor, nN, nb);
    }
    scatter_b<<<8 * 256, 256, 0, stream>>>(staging, bucketCursor, BUCKET_CAP, cursor, ep, 256);

    const int aggBlocks = 2048;         // persistent waves: 8192 waves, grid-stride
    const int gBlocks = cdiv(nN, 128);

    const void* A = useXbf ? (const void*)xbf : (const void*)x;
    for (int L = 0; L < 9; ++L) {
        int fi = dims[L], fo = dims[L + 1];
        if (L == 8) {
            // final layer: uint8 supp (64 cols, cols 40..63 zero rows in Wt), per-row scale
            dim3 g(gBlocks, 1);
            gemm_mfma<64, false, 2><<<g, 256, 0, stream>>>(A, Wt + woff[L], (void*)supp8,
                                                           scArr, nN, fi, 64);
            agg_lsm_q8<<<aggBlocks, 256, 0, stream>>>(supp8, scArr, ep, rowptr, b[8],
                                                      (float*)d_out, nN);
            break;
        }
        if (fo == 256) {
            dim3 g(gBlocks, 2);
            if (L == 0 && !useXbf)
                gemm_mfma<128, true, 1><<<g, 256, 0, stream>>>(A, Wt + woff[L], (void*)supp8,
                                                               scArr, nN, fi, fo);
            else
                gemm_mfma<128, false, 1><<<g, 256, 0, stream>>>(A, Wt + woff[L], (void*)supp8,
                                                                scArr, nN, fi, fo);
            agg_q8<256><<<aggBlocks, 256, 0, stream>>>(supp8, scArr, ep, rowptr, b[L], h, nN);
        } else if (fo == 128) {
            dim3 g(gBlocks, 1);
            gemm_mfma<128, false, 1><<<g, 256, 0, stream>>>(A, Wt + woff[L], (void*)supp8,
                                                            scArr, nN, fi, fo);
            agg_q8<128><<<aggBlocks, 256, 0, stream>>>(supp8, scArr, ep, rowptr, b[L], h, nN);
        } else {  // fo == 64 (L7): uint8 path, per-row scale
            dim3 g(gBlocks, 1);
            gemm_mfma<64, false, 2><<<g, 256, 0, stream>>>(A, Wt + woff[L], (void*)supp8,
                                                           scArr, nN, fi, 64);
            agg_q8<64><<<aggBlocks, 256, 0, stream>>>(supp8, scArr, ep, rowptr, b[L], h, nN);
        }
        A = (const void*)h;
    }
}

// Round 18
// 1653.347 us; speedup vs baseline: 1.0179x; 1.0179x over previous
//
#include <hip/hip_runtime.h>
#include <cstdint>
#include <cstddef>

typedef __attribute__((ext_vector_type(8))) short bf16x8;   // 8 bf16 in 4 VGPRs
typedef __attribute__((ext_vector_type(4))) float f32x4;    // MFMA accumulator
typedef __attribute__((ext_vector_type(4))) int i32x4;      // nt-load payload

static inline int cdiv(int a, int b) { return (a + b - 1) / b; }

__device__ inline unsigned short f2bf(float f) {
    union { float f; unsigned int u; } v; v.f = f;
    unsigned int u = v.u;
    return (unsigned short)((u + 0x7FFFu + ((u >> 16) & 1u)) >> 16);  // RNE
}
__device__ inline float bf2f(unsigned short b) {
    union { unsigned int u; float f; } v; v.u = ((unsigned int)b) << 16;
    return v.f;
}

// dequant 16 biased-uint8 (excess-128) with weight*scale; caller subtracts 128*wsum.
__device__ inline void fma16u(float* a, const int4& d, float ws) {
    const unsigned int dw[4] = {(unsigned)d.x, (unsigned)d.y, (unsigned)d.z, (unsigned)d.w};
#pragma unroll
    for (int w = 0; w < 4; ++w) {
        a[w * 4 + 0] += ws * (float)(dw[w] & 0xFFu);
        a[w * 4 + 1] += ws * (float)((dw[w] >> 8) & 0xFFu);
        a[w * 4 + 2] += ws * (float)((dw[w] >> 16) & 0xFFu);
        a[w * 4 + 3] += ws * (float)(dw[w] >> 24);
    }
}

// ---------------- prep: weight transposes (f32->bf16, [fo_pad][fi]) + zero deg/bucketCursor ----------------

struct TW {
    const float* W[9];
    int K[9];
    int N[9];
    int base[10];
    int nN;
};

__global__ __launch_bounds__(256) void prep_kernel(TW tw, unsigned short* __restrict__ Wt,
                                                   int* __restrict__ deg,
                                                   int* __restrict__ bucketCursor, int total) {
    int t = blockIdx.x * 256 + threadIdx.x;
    if (t < tw.nN) deg[t] = 0;
    if (t < 8) bucketCursor[t] = 0;
    if (t >= total) return;
    int l = 0;
#pragma unroll
    for (int i = 1; i <= 8; ++i)
        if (t >= tw.base[i]) l = i;
    int loc = t - tw.base[l];
    int K = tw.K[l], N = tw.N[l];
    int n = loc / K, k = loc - n * K;
    float v = (n < N) ? tw.W[l][(size_t)k * N + n] : 0.f;
    Wt[t] = f2bf(v);
}

// ---------------- phase A: persistent bucket partition, wave-aggregated atomics ----------------

#define PB_BLOCKS 2048

__global__ __launch_bounds__(256) void partition_v2(
        const int* __restrict__ src, const int* __restrict__ dst,
        const float* __restrict__ w,
        int* __restrict__ bucketCursor, int4* __restrict__ staging,
        int bucketCap, int nE, int nN) {
    __shared__ int cnt[8];
    __shared__ int cur[8];
    const int tid = threadIdx.x;
    const int lane = tid & 63;
    const int perBlock = (nE + (int)gridDim.x - 1) / (int)gridDim.x;
    const int begE = blockIdx.x * perBlock;
    const int endE = (begE + perBlock < nE) ? begE + perBlock : nE;
    if (begE >= endE) return;
    if (tid < 8) cnt[tid] = 0;
    __syncthreads();
    for (int i = begE + tid; i < endE; i += 256) {
        int d = dst[i];
        int b = (int)(((long long)d * 8) / nN);
#pragma unroll
        for (int bb = 0; bb < 8; ++bb) {
            unsigned long long mask = __ballot(b == bb);
            if (mask && lane == (__ffsll(mask) - 1))
                atomicAdd(&cnt[bb], (int)__popcll(mask));
        }
    }
    __syncthreads();
    if (tid < 8) cur[tid] = atomicAdd(&bucketCursor[tid], cnt[tid]);
    __syncthreads();
    for (int i = begE + tid; i < endE; i += 256) {
        int d = dst[i], s = src[i];
        float wv = w[i];
        int b = (int)(((long long)d * 8) / nN);
        int pos = 0;
#pragma unroll
        for (int bb = 0; bb < 8; ++bb) {
            unsigned long long mask = __ballot(b == bb);
            int leader = mask ? (__ffsll(mask) - 1) : 0;
            int base_bb = 0;
            if (mask && lane == leader) base_bb = atomicAdd(&cur[bb], (int)__popcll(mask));
            base_bb = __shfl(base_bb, leader);
            if (b == bb) pos = base_bb + (int)__popcll(mask & ((1ull << lane) - 1ull));
        }
        staging[(size_t)b * bucketCap + pos] = make_int4(d, s, __float_as_int(wv), 0);
    }
}

// ---------------- bucketed deg count: LDS histogram per block, nt streaming reads ----------------

#define DC_BPB 32

__global__ __launch_bounds__(256) void deg_count(const int4* __restrict__ staging,
                                                 const int* __restrict__ bucketCnt,
                                                 int bucketCap, int* __restrict__ deg, int nN) {
    __shared__ int hist[12512];
    int bucket = blockIdx.x & 7;
    int chunk = blockIdx.x >> 3;
    int cnt = bucketCnt[bucket];
    int lo = (int)(((long long)bucket * nN + 7) / 8);
    int hi = (int)(((long long)(bucket + 1) * nN + 7) / 8);
    if (hi > nN) hi = nN;
    int span = hi - lo;
    for (int i = threadIdx.x; i < span; i += 256) hist[i] = 0;
    __syncthreads();
    const i32x4* st = (const i32x4*)(staging + (size_t)bucket * bucketCap);
    for (int i = chunk * 256 + threadIdx.x; i < cnt; i += DC_BPB * 256) {
        i32x4 r = __builtin_nontemporal_load(&st[i]);
        atomicAdd(&hist[r[0] - lo], 1);
    }
    __syncthreads();
    for (int i = threadIdx.x; i < span; i += 256) {
        int v = hist[i];
        if (v) atomicAdd(&deg[lo + i], v);
    }
}

// ---------------- scan: per-block sums, then fused (partial-scan + final) ----------------

__global__ __launch_bounds__(256) void scan_part(const int* __restrict__ deg,
                                                 int* __restrict__ partials, int n) {
    __shared__ int sdata[256];
    int tid = threadIdx.x;
    int base = blockIdx.x * 1024;
    int local = 0;
#pragma unroll
    for (int i = 0; i < 4; ++i) {
        int idx = base + tid * 4 + i;
        local += (idx < n) ? deg[idx] : 0;
    }
    sdata[tid] = local;
    __syncthreads();
    for (int off = 128; off; off >>= 1) {
        if (tid < off) sdata[tid] += sdata[tid + off];
        __syncthreads();
    }
    if (tid == 0) partials[blockIdx.x] = sdata[0];
}

__global__ __launch_bounds__(256) void scan_final2(const int* __restrict__ deg,
                                                   const int* __restrict__ partials,
                                                   int* __restrict__ rowptr,
                                                   int* __restrict__ cursor, int n, int nb) {
    __shared__ int ps[128];
    __shared__ int sdata[256];
    int tid = threadIdx.x;
    if (tid < 128) ps[tid] = (tid < nb) ? partials[tid] : 0;
    __syncthreads();
    for (int off = 1; off < 128; off <<= 1) {
        int t = (tid < 128 && tid >= off) ? ps[tid - off] : 0;
        __syncthreads();
        if (tid < 128) ps[tid] += t;
        __syncthreads();
    }
    int base = (blockIdx.x == 0) ? 0 : ps[blockIdx.x - 1];
    if (blockIdx.x == 0 && tid == 0) rowptr[n] = ps[nb - 1];
    int bb = blockIdx.x * 1024;
    int vals[4];
    int local = 0;
#pragma unroll
    for (int i = 0; i < 4; ++i) {
        int idx = bb + tid * 4 + i;
        vals[i] = (idx < n) ? deg[idx] : 0;
        local += vals[i];
    }
    sdata[tid] = local;
    __syncthreads();
    for (int off = 1; off < 256; off <<= 1) {
        int t = (tid >= off) ? sdata[tid - off] : 0;
        __syncthreads();
        sdata[tid] += t;
        __syncthreads();
    }
    int run = sdata[tid] - local + base;
#pragma unroll
    for (int i = 0; i < 4; ++i) {
        int idx = bb + tid * 4 + i;
        if (idx < n) { rowptr[idx] = run; cursor[idx] = run; }
        run += vals[i];
    }
}

// ---------------- phase B: per-bucket scatter, nt streaming reads (ep lines stay L2-resident) ----------------

__global__ __launch_bounds__(256) void scatter_b(const int4* __restrict__ staging,
                                                 const int* __restrict__ bucketCnt,
                                                 int bucketCap, int* __restrict__ cursor,
                                                 int2* __restrict__ ep, int blocksPerBucket) {
    int bucket = blockIdx.x & 7;
    int chunk = blockIdx.x >> 3;
    int cnt = bucketCnt[bucket];
    const i32x4* st = (const i32x4*)(staging + (size_t)bucket * bucketCap);
    for (int i = chunk * 256 + threadIdx.x; i < cnt; i += blocksPerBucket * 256) {
        i32x4 r = __builtin_nontemporal_load(&st[i]);
        int pos = atomicAdd(&cursor[r[0]], 1);
        ep[pos] = make_int2(r[1], r[2]);
    }
}

// ---------------- bf16 MFMA GEMM (m97 structure): C[M,N] = A[M,K] @ Bt[N,K]^T ----------------
// OUTQ: 0 = bf16 out; 1 = biased-uint8 out, per-(row,128-col-block) scale (BN=128);
//       2 = biased-uint8 out, per-row scale (BN=64, single column block).

template <int BN, bool AF32, int OUTQ>
__global__ __launch_bounds__(256) void gemm_mfma(const void* __restrict__ Av,
                                                 const unsigned short* __restrict__ Bt,
                                                 void* __restrict__ Cv,
                                                 float* __restrict__ scArr,
                                                 int M, int K, int N) {
    constexpr int BM = 128, BK = 64;
    __shared__ unsigned short As[BM * BK];
    __shared__ unsigned short Bs[BN * BK];
    const int tid = threadIdx.x;
    const int lane = tid & 63, wid = tid >> 6;
    const int m0 = blockIdx.x * BM, n0 = blockIdx.y * BN;

    constexpr int WN = (BN == 128) ? 2 : 1;
    constexpr int WTM = (BN == 128) ? 64 : 32;
    constexpr int FM = WTM / 16, FN = 4;
    const int wm = (wid / WN) * WTM;
    const int wn = (wid % WN) * 64;
    const int g = lane >> 4, r16 = lane & 15;

    const unsigned short* A16 = (const unsigned short*)Av;
    const float* A32 = (const float*)Av;

    f32x4 acc[FM][FN] = {};

    for (int k0 = 0; k0 < K; k0 += BK) {
        if constexpr (AF32) {
#pragma unroll
            for (int it = 0; it < 4; ++it) {
                int c = it * 256 + tid;
                int r = c >> 3, kc = c & 7;
                int gm = m0 + r;
                bf16x8 val;
                if (gm < M) {
                    const float* p = A32 + (size_t)gm * K + k0 + kc * 8;
                    float4 v0 = *reinterpret_cast<const float4*>(p);
                    float4 v1 = *reinterpret_cast<const float4*>(p + 4);
                    val[0] = (short)f2bf(v0.x); val[1] = (short)f2bf(v0.y);
                    val[2] = (short)f2bf(v0.z); val[3] = (short)f2bf(v0.w);
                    val[4] = (short)f2bf(v1.x); val[5] = (short)f2bf(v1.y);
                    val[6] = (short)f2bf(v1.z); val[7] = (short)f2bf(v1.w);
                } else {
#pragma unroll
                    for (int j = 0; j < 8; ++j) val[j] = 0;
                }
                *reinterpret_cast<bf16x8*>(&As[r * BK + kc * 8]) = val;
            }
        } else {
#pragma unroll
            for (int c = 0; c < 4; ++c) {
                int base = wid * 32 + c * 8;
                int row = base + (lane >> 3), kc = lane & 7;
                const unsigned short* gp = A16 + (size_t)(m0 + row) * K + k0 + kc * 8;
                __builtin_amdgcn_global_load_lds(
                    (const __attribute__((address_space(1))) void*)gp,
                    (__attribute__((address_space(3))) void*)&As[base * BK], 16, 0, 0);
            }
        }
        {
            constexpr int BCALLS = (BN * BK) / (512 * 4);
#pragma unroll
            for (int c = 0; c < BCALLS; ++c) {
                int base = wid * (BN / 4) + c * 8;
                int row = base + (lane >> 3), kc = lane & 7;
                const unsigned short* gp = Bt + (size_t)(n0 + row) * K + k0 + kc * 8;
                __builtin_amdgcn_global_load_lds(
                    (const __attribute__((address_space(1))) void*)gp,
                    (__attribute__((address_space(3))) void*)&Bs[base * BK], 16, 0, 0);
            }
        }
        __syncthreads();
#pragma unroll
        for (int ks = 0; ks < 2; ++ks) {
            bf16x8 af[FM], bfr[FN];
#pragma unroll
            for (int i = 0; i < FM; ++i)
                af[i] = *reinterpret_cast<const bf16x8*>(&As[(wm + i * 16 + r16) * BK + ks * 32 + g * 8]);
#pragma unroll
            for (int j = 0; j < FN; ++j)
                bfr[j] = *reinterpret_cast<const bf16x8*>(&Bs[(wn + j * 16 + r16) * BK + ks * 32 + g * 8]);
#pragma unroll
            for (int i = 0; i < FM; ++i)
#pragma unroll
                for (int j = 0; j < FN; ++j)
                    acc[i][j] = __builtin_amdgcn_mfma_f32_16x16x32_bf16(af[i], bfr[j], acc[i][j], 0, 0, 0);
        }
        __syncthreads();
    }

    if constexpr (OUTQ == 1) {
        __shared__ float rmax2[2][BM];
        const int wc = wid % WN;
        unsigned char* C8 = (unsigned char*)Cv;
#pragma unroll
        for (int i = 0; i < FM; ++i) {
#pragma unroll
            for (int r = 0; r < 4; ++r) {
                float m = 0.f;
#pragma unroll
                for (int j = 0; j < FN; ++j) m = fmaxf(m, fabsf(acc[i][j][r]));
                m = fmaxf(m, __shfl_xor(m, 1));
                m = fmaxf(m, __shfl_xor(m, 2));
                m = fmaxf(m, __shfl_xor(m, 4));
                m = fmaxf(m, __shfl_xor(m, 8));
                if (r16 == 0) rmax2[wc][wm + i * 16 + g * 4 + r] = m;
            }
        }
        __syncthreads();
#pragma unroll
        for (int i = 0; i < FM; ++i) {
#pragma unroll
            for (int r = 0; r < 4; ++r) {
                int rl = wm + i * 16 + g * 4 + r;
                float rm = fmaxf(rmax2[0][rl], rmax2[1][rl]);
                float inv = (rm > 0.f) ? 127.f / rm : 0.f;
                int gm = m0 + rl;
                if (gm < M) {
                    if (wc == 0 && r16 == 0)
                        scArr[(size_t)gm * 2 + blockIdx.y] = rm * (1.f / 127.f);
#pragma unroll
                    for (int j = 0; j < FN; ++j) {
                        int gn = n0 + wn + j * 16 + r16;
                        float q = fminf(fmaxf(rintf(acc[i][j][r] * inv), -127.f), 127.f);
                        C8[(size_t)gm * N + gn] = (unsigned char)((int)q + 128);
                    }
                }
            }
        }
    } else if constexpr (OUTQ == 2) {
        unsigned char* C8 = (unsigned char*)Cv;
#pragma unroll
        for (int i = 0; i < FM; ++i) {
#pragma unroll
            for (int r = 0; r < 4; ++r) {
                float m = 0.f;
#pragma unroll
                for (int j = 0; j < FN; ++j) m = fmaxf(m, fabsf(acc[i][j][r]));
                m = fmaxf(m, __shfl_xor(m, 1));
                m = fmaxf(m, __shfl_xor(m, 2));
                m = fmaxf(m, __shfl_xor(m, 4));
                m = fmaxf(m, __shfl_xor(m, 8));
                float inv = (m > 0.f) ? 127.f / m : 0.f;
                int gm = m0 + wm + i * 16 + g * 4 + r;
                if (gm < M) {
                    if (r16 == 0) scArr[(size_t)gm * 2] = m * (1.f / 127.f);
#pragma unroll
                    for (int j = 0; j < FN; ++j) {
                        int gn = wn + j * 16 + r16;
                        float q = fminf(fmaxf(rintf(acc[i][j][r] * inv), -127.f), 127.f);
                        C8[(size_t)gm * 64 + gn] = (unsigned char)((int)q + 128);
                    }
                }
            }
        }
    } else {
        unsigned short* C = (unsigned short*)Cv;
#pragma unroll
        for (int i = 0; i < FM; ++i) {
            int gmBase = m0 + wm + i * 16 + g * 4;
#pragma unroll
            for (int j = 0; j < FN; ++j) {
                int gn = n0 + wn + j * 16 + r16;
                if (gn < N) {
#pragma unroll
                    for (int r = 0; r < 4; ++r) {
                        int gm = gmBase + r;
                        if (gm < M) C[(size_t)gm * N + gn] = f2bf(acc[i][j][r]);
                    }
                }
            }
        }
    }
}

// ---------------- biased-uint8 CSR aggregation, persistent grid-stride waves ----------------

template <int FO>
__global__ __launch_bounds__(256) void agg_q8(const char* __restrict__ supp8,
                                              const float* __restrict__ sc,
                                              const int2* __restrict__ ep,
                                              const int* __restrict__ rowptr,
                                              const float* __restrict__ bias,
                                              unsigned short* __restrict__ out, int n_nodes) {
    constexpr int LPR = FO / 16;
    constexpr int EPS = 64 / LPR;
    constexpr int G16 = 16 / EPS;
    constexpr int G8 = 8 / EPS;
    constexpr int TG = (FO == 256) ? 2 : 1;
    const int wave0 = (int)((blockIdx.x * blockDim.x + threadIdx.x) >> 6);
    const int nWaves = (int)((gridDim.x * blockDim.x) >> 6);
    const int lane = threadIdx.x & 63;
    const int lr = lane & (LPR - 1);
    const int half = lane / LPR;
    const int hi = (FO == 256) ? (lr >> 3) : 0;

    for (int node = wave0; node < n_nodes; node += nWaves) {
        int beg = __builtin_amdgcn_readfirstlane(rowptr[node]);
        int end = __builtin_amdgcn_readfirstlane(rowptr[node + 1]);
        float a[16] = {};
        float wsum = 0.f;
        int e = beg;
        for (; e + 16 <= end; e += 16) {
            int2 me[G16];
#pragma unroll
            for (int u = 0; u < G16; ++u) me[u] = ep[e + u * EPS + half];
            float ss[G16];
            int4 q[G16];
#pragma unroll
            for (int u = 0; u < G16; ++u) ss[u] = sc[(size_t)me[u].x * 2 + hi];
#pragma unroll
            for (int u = 0; u < G16; ++u)
                q[u] = *reinterpret_cast<const int4*>(supp8 + (size_t)me[u].x * FO + lr * 16);
#pragma unroll
            for (int u = 0; u < G16; ++u) {
                float ws = __int_as_float(me[u].y) * ss[u];
                fma16u(a, q[u], ws);
                wsum += ws;
            }
        }
        if constexpr (G8 >= 1) {
            for (; e + 8 <= end; e += 8) {
                int2 me[G8];
#pragma unroll
                for (int u = 0; u < G8; ++u) me[u] = ep[e + u * EPS + half];
                float ss[G8];
                int4 q[G8];
#pragma unroll
                for (int u = 0; u < G8; ++u) ss[u] = sc[(size_t)me[u].x * 2 + hi];
#pragma unroll
                for (int u = 0; u < G8; ++u)
                    q[u] = *reinterpret_cast<const int4*>(supp8 + (size_t)me[u].x * FO + lr * 16);
#pragma unroll
                for (int u = 0; u < G8; ++u) {
                    float ws = __int_as_float(me[u].y) * ss[u];
                    fma16u(a, q[u], ws);
                    wsum += ws;
                }
            }
        }
        {
            int rem = end - e;
            if (rem > 0) {
#pragma unroll
                for (int u = 0; u < TG; ++u) {
                    int idx = u * EPS + half;
                    bool ok = idx < rem;
                    int2 me = ep[e + (ok ? idx : 0)];
                    float ws = ok ? __int_as_float(me.y) * sc[(size_t)me.x * 2 + hi] : 0.f;
                    int4 q = *reinterpret_cast<const int4*>(supp8 + (size_t)me.x * FO + lr * 16);
                    fma16u(a, q, ws);
                    wsum += ws;
                }
            }
        }
#pragma unroll
        for (int j = 0; j < 16; ++j) a[j] -= 128.f * wsum;
#pragma unroll
        for (int off = LPR; off < 64; off <<= 1)
#pragma unroll
            for (int j = 0; j < 16; ++j) a[j] += __shfl_xor(a[j], off);
        if (lane < LPR) {
            float bb[16];
#pragma unroll
            for (int c = 0; c < 4; ++c) {
                float4 bv = *reinterpret_cast<const float4*>(bias + lr * 16 + c * 4);
                bb[c * 4 + 0] = bv.x; bb[c * 4 + 1] = bv.y;
                bb[c * 4 + 2] = bv.z; bb[c * 4 + 3] = bv.w;
            }
            bf16x8 o0, o1;
#pragma unroll
            for (int j = 0; j < 8; ++j) {
                o0[j] = (short)f2bf(fmaxf(a[j] + bb[j], 0.f));
                o1[j] = (short)f2bf(fmaxf(a[j + 8] + bb[j + 8], 0.f));
            }
            unsigned short* op = out + (size_t)node * FO + lr * 16;
            *reinterpret_cast<bf16x8*>(op) = o0;
            *reinterpret_cast<bf16x8*>(op + 8) = o1;
        }
    }
}

// ---------------- final layer: padded-64 supp, agg + bias + log_softmax, grid-stride ----------------

__global__ __launch_bounds__(256) void agg_lsm_kernel(const unsigned short* __restrict__ supp,
                                                      const int2* __restrict__ ep,
                                                      const int* __restrict__ rowptr,
                                                      const float* __restrict__ bias,
                                                      float* __restrict__ out, int n_nodes) {
    const int wave0 = (int)((blockIdx.x * blockDim.x + threadIdx.x) >> 6);
    const int nWaves = (int)((gridDim.x * blockDim.x) >> 6);
    const int lane = threadIdx.x & 63;
    const int lr = lane & 7;
    const int half = lane >> 3;

    for (int node = wave0; node < n_nodes; node += nWaves) {
        int beg = __builtin_amdgcn_readfirstlane(rowptr[node]);
        int end = __builtin_amdgcn_readfirstlane(rowptr[node + 1]);
        float a[8] = {};
        int e = beg;
        for (; e + 16 <= end; e += 16) {
            int2 me0 = ep[e + half];
            int2 me1 = ep[e + 8 + half];
            bf16x8 v0 = *reinterpret_cast<const bf16x8*>(supp + (size_t)me0.x * 64 + lr * 8);
            bf16x8 v1 = *reinterpret_cast<const bf16x8*>(supp + (size_t)me1.x * 64 + lr * 8);
            float w0 = __int_as_float(me0.y), w1 = __int_as_float(me1.y);
#pragma unroll
            for (int j = 0; j < 8; ++j)
                a[j] += w0 * bf2f((unsigned short)v0[j]) + w1 * bf2f((unsigned short)v1[j]);
        }
        {
            int rem = end - e;
            if (rem > 0) {
#pragma unroll
                for (int u = 0; u < 2; ++u) {
                    int idx = u * 8 + half;
                    bool ok = idx < rem;
                    int2 me = ep[e + (ok ? idx : 0)];
                    float wv = ok ? __int_as_float(me.y) : 0.f;
                    bf16x8 v = *reinterpret_cast<const bf16x8*>(supp + (size_t)me.x * 64 + lr * 8);
#pragma unroll
                    for (int j = 0; j < 8; ++j) a[j] += wv * bf2f((unsigned short)v[j]);
                }
            }
        }
#pragma unroll
        for (int off = 8; off < 64; off <<= 1)
#pragma unroll
            for (int j = 0; j < 8; ++j) a[j] += __shfl_xor(a[j], off);
        float vj[8];
#pragma unroll
        for (int j = 0; j < 8; ++j) {
            int col = lane * 8 + j;
            float bv = (lane < 8 && col < 40) ? bias[col] : 0.f;
            vj[j] = (col < 40) ? (a[j] + bv) : -1e30f;
        }
        float m = vj[0];
#pragma unroll
        for (int j = 1; j < 8; ++j) m = fmaxf(m, vj[j]);
#pragma unroll
        for (int off = 1; off < 8; off <<= 1) m = fmaxf(m, __shfl_xor(m, off));
        float s = 0.f;
#pragma unroll
        for (int j = 0; j < 8; ++j) s += expf(vj[j] - m);
#pragma unroll
        for (int off = 1; off < 8; off <<= 1) s += __shfl_xor(s, off);
        float ls = m + logf(s);
        if (lane < 5) {
            float4 o0, o1;
            o0.x = vj[0] - ls; o0.y = vj[1] - ls; o0.z = vj[2] - ls; o0.w = vj[3] - ls;
            o1.x = vj[4] - ls; o1.y = vj[5] - ls; o1.z = vj[6] - ls; o1.w = vj[7] - ls;
            float* op = out + (size_t)node * 40 + lane * 8;
            *reinterpret_cast<float4*>(op) = o0;
            *reinterpret_cast<float4*>(op + 4) = o1;
        }
    }
}

// ---------------- launch ----------------

extern "C" void kernel_launch(void* const* d_in, const int* in_sizes, int n_in,
                              void* d_out, int out_size, void* d_ws, size_t ws_size,
                              hipStream_t stream) {
    const float* x    = (const float*)d_in[0];
    const int*   esrc = (const int*)d_in[1];
    const int*   edst = (const int*)d_in[2];
    const float* ew   = (const float*)d_in[3];

    const int nN = in_sizes[0] / 512;  // 100000
    const int nE = in_sizes[1];        // 3200000

    const int dims[10] = {512, 256, 256, 256, 256, 256, 128, 128, 64, 40};
    const int BUCKET_CAP = ((nE / 8) + (nE / 64) + 4095) & ~4095;

    // ---- workspace layout (GEMM A-tile tail blocks read up to ~50KB past h; supp follows) ----
    char* ws = (char*)d_ws;
    unsigned short* h    = (unsigned short*)ws;                       // nN*256 bf16
    unsigned short* supp = (unsigned short*)(ws + (size_t)nN * 256 * 2);
    char* supp8 = (char*)supp;                                        // uint8 view (same region)
    char* p = ws + (size_t)nN * 256 * 2 * 2;
    unsigned short* Wt = (unsigned short*)p; p += (1 << 21);
    float* scArr  = (float*)p; p += (size_t)nN * 2 * 4 + 256;
    int4* staging = (int4*)p; p += (size_t)8 * BUCKET_CAP * 16;
    int* deg      = (int*)p; p += ((size_t)nN + 64) * 4;
    int* rowptr   = (int*)p; p += ((size_t)nN + 64) * 4;
    int* cursor   = (int*)p; p += ((size_t)nN + 64) * 4;
    int* partials = (int*)p; p += 128 * 4;
    int* bucketCursor = (int*)p; p += 64 * 4;
    int2* ep      = (int2*)p; p += (size_t)nE * 8;

    // ---- prep: transpose+convert weights, zero deg/bucketCursor ----
    TW tw;
    size_t woff[9];
    {
        int off = 0;
        for (int i = 0; i < 9; ++i) {
            tw.W[i] = (const float*)d_in[4 + 2 * i];
            tw.K[i] = dims[i];
            tw.N[i] = dims[i + 1];
            tw.base[i] = off;
            woff[i] = (size_t)off;
            int fop = cdiv(dims[i + 1], 64) * 64;
            off += fop * dims[i];
        }
        tw.base[9] = off;
        tw.nN = nN;
        int total = off;
        int nPrep = cdiv((total > nN + 8) ? total : nN + 8, 256);
        prep_kernel<<<nPrep, 256, 0, stream>>>(tw, Wt, deg, bucketCursor, total);
    }
    const float* b[9];
    for (int i = 0; i < 9; ++i) b[i] = (const float*)d_in[5 + 2 * i];

    // ---- CSR build: partition_v2 -> bucketed deg count -> scan -> per-bucket scatter ----
    partition_v2<<<PB_BLOCKS, 256, 0, stream>>>(esrc, edst, ew, bucketCursor,
                                                staging, BUCKET_CAP, nE, nN);
    deg_count<<<8 * DC_BPB, 256, 0, stream>>>(staging, bucketCursor, BUCKET_CAP, deg, nN);
    {
        int nb = cdiv(nN, 1024);
        scan_part<<<nb, 256, 0, stream>>>(deg, partials, nN);
        scan_final2<<<nb, 256, 0, stream>>>(deg, partials, rowptr, cursor, nN, nb);
    }
    scatter_b<<<8 * 256, 256, 0, stream>>>(staging, bucketCursor, BUCKET_CAP, cursor, ep, 256);

    const int aggBlocks = 2048;         // persistent waves: 8192 waves, grid-stride over nodes
    const int gBlocks = cdiv(nN, 128);

    const void* A = (const void*)x;
    for (int L = 0; L < 9; ++L) {
        int fi = dims[L], fo = dims[L + 1];
        if (L == 8) {
            // padded final layer (bf16): compute 64 cols (40..63 zeros), stride 64
            dim3 g(gBlocks, 1);
            gemm_mfma<64, false, 0><<<g, 256, 0, stream>>>(A, Wt + woff[L], (void*)supp,
                                                           scArr, nN, fi, 64);
            agg_lsm_kernel<<<aggBlocks, 256, 0, stream>>>(supp, ep, rowptr, b[8], (float*)d_out, nN);
            break;
        }
        if (fo == 256) {
            dim3 g(gBlocks, 2);
            if (L == 0)
                gemm_mfma<128, true, 1><<<g, 256, 0, stream>>>(A, Wt + woff[L], (void*)supp8,
                                                               scArr, nN, fi, fo);
            else
                gemm_mfma<128, false, 1><<<g, 256, 0, stream>>>(A, Wt + woff[L], (void*)supp8,
                                                                scArr, nN, fi, fo);
            agg_q8<256><<<aggBlocks, 256, 0, stream>>>(supp8, scArr, ep, rowptr, b[L], h, nN);
        } else if (fo == 128) {
            dim3 g(gBlocks, 1);
            gemm_mfma<128, false, 1><<<g, 256, 0, stream>>>(A, Wt + woff[L], (void*)supp8,
                                                            scArr, nN, fi, fo);
            agg_q8<128><<<aggBlocks, 256, 0, stream>>>(supp8, scArr, ep, rowptr, b[L], h, nN);
        } else {  // fo == 64 (L7): uint8 path, per-row scale
            dim3 g(gBlocks, 1);
            gemm_mfma<64, false, 2><<<g, 256, 0, stream>>>(A, Wt + woff[L], (void*)supp8,
                                                           scArr, nN, fi, 64);
            agg_q8<64><<<aggBlocks, 256, 0, stream>>>(supp8, scArr, ep, rowptr, b[L], h, nN);
        }
        A = (const void*)h;
    }
}